// Round 6
// baseline (401.425 us; speedup 1.0000x reference)
//
#include <hip/hip_runtime.h>
#include <hip/hip_bf16.h>
#include <math.h>

#define NTOK 8192
#define CDIM 1024
#define NEXP 8
#define FFD  2048
#define RMAX    18432   /* 2*NTOK + NEXP*256 (256-pad) */
#define RMAX128 17408   /* 2*NTOK + NEXP*128 (fallback) */

typedef __attribute__((ext_vector_type(8))) short short8;
typedef __attribute__((ext_vector_type(4))) float f32x4;

__device__ __forceinline__ unsigned short f2b(float f){
    __hip_bfloat16 b = __float2bfloat16(f);
    return *reinterpret_cast<unsigned short*>(&b);
}
__device__ __forceinline__ float b2f(unsigned short u){
    __hip_bfloat16 b = *reinterpret_cast<__hip_bfloat16*>(&u);
    return __bfloat162float(b);
}

/* async global->LDS, 16B per lane; LDS dest = wave-uniform base + lane*16 */
__device__ __forceinline__ void gl_lds16(const void* g, void* l){
    __builtin_amdgcn_global_load_lds(
        (const __attribute__((address_space(1))) unsigned int*)g,
        (__attribute__((address_space(3))) unsigned int*)l, 16, 0, 0);
}

/* ---------------- f32 -> bf16 bulk convert (weights) ---------------- */
__global__ void k_cvt(const float* __restrict__ src, unsigned short* __restrict__ dst, int n8){
    int i = blockIdx.x*blockDim.x + threadIdx.x;
    if(i >= n8) return;
    const float4* s = reinterpret_cast<const float4*>(src) + (size_t)i*2;
    float4 a = s[0], b = s[1];
    ushort4 o0 = { f2b(a.x), f2b(a.y), f2b(a.z), f2b(a.w) };
    ushort4 o1 = { f2b(b.x), f2b(b.y), f2b(b.z), f2b(b.w) };
    ushort4* d = reinterpret_cast<ushort4*>(dst) + (size_t)i*2;
    d[0] = o0; d[1] = o1;
}

/* ---------------- fused gate + x->bf16 (NO atomics) ---------------- */
__global__ void k_gate(const float* __restrict__ x, const float* __restrict__ gw,
                       unsigned short* __restrict__ Xb,
                       int* __restrict__ eidx, float* __restrict__ probs){
    int tok  = blockIdx.x*4 + (threadIdx.x>>6);
    int l    = threadIdx.x & 63;
    const float4* xr  = reinterpret_cast<const float4*>(x + (size_t)tok*CDIM);
    ushort4*      xbw = reinterpret_cast<ushort4*>(Xb + (size_t)tok*CDIM);
    float acc[NEXP];
    #pragma unroll
    for(int e=0;e<NEXP;e++) acc[e]=0.f;
    #pragma unroll
    for(int i=0;i<4;i++){
        float4 v = xr[l + 64*i];
        ushort4 o = { f2b(v.x), f2b(v.y), f2b(v.z), f2b(v.w) };
        xbw[l + 64*i] = o;
        #pragma unroll
        for(int e=0;e<NEXP;e++){
            float4 g = reinterpret_cast<const float4*>(gw + e*CDIM)[l + 64*i];
            acc[e] += v.x*g.x + v.y*g.y + v.z*g.z + v.w*g.w;
        }
    }
    #pragma unroll
    for(int e=0;e<NEXP;e++){
        #pragma unroll
        for(int off=32; off; off>>=1) acc[e] += __shfl_xor(acc[e], off);
    }
    if(l==0){
        int e0=0; float s0=acc[0];
        #pragma unroll
        for(int e=1;e<NEXP;e++) if(acc[e]>s0){s0=acc[e]; e0=e;}
        int e1=-1; float s1=-1e30f;
        #pragma unroll
        for(int e=0;e<NEXP;e++) if(e!=e0 && acc[e]>s1){s1=acc[e]; e1=e;}
        float p0 = 1.f/(1.f + expf(s1-s0));
        float p1 = 1.f - p0;
        eidx[2*tok]=e0;  eidx[2*tok+1]=e1;
        probs[2*tok]=p0; probs[2*tok+1]=p1;
    }
}

/* ---------------- deterministic rank (slot) + aoff: ONE block, no atomics ---- */
__global__ void k_rank(const int* __restrict__ eidx, int* __restrict__ slot,
                       int* __restrict__ aoff, int pad){
    __shared__ int run[NEXP];
    __shared__ int wavehist[16][NEXP];
    int tid  = threadIdx.x;              /* 1024 threads = 16 waves */
    int lane = tid & 63, w = tid >> 6;
    if(tid < NEXP) run[tid] = 0;
    __syncthreads();
    for(int iter=0; iter<(2*NTOK)/1024; iter++){
        int t = iter*1024 + tid;
        int e = eidx[t];
        unsigned long long mymask = 0;
        #pragma unroll
        for(int ee=0; ee<NEXP; ee++){
            unsigned long long m = __ballot(e==ee);
            if(ee==e) mymask = m;
            if(lane==0) wavehist[w][ee] = __popcll(m);
        }
        int lanerank = __popcll(mymask & ((1ULL<<lane)-1ULL));
        __syncthreads();
        if(tid < NEXP){
            int base = run[tid];
            #pragma unroll
            for(int ww=0; ww<16; ww++){
                int c = wavehist[ww][tid];
                wavehist[ww][tid] = base;
                base += c;
            }
            run[tid] = base;
        }
        __syncthreads();
        slot[t] = wavehist[w][e] + lanerank;
    }
    __syncthreads();
    if(tid==0){
        int off=0;
        for(int e=0;e<NEXP;e++){ aoff[e]=off; off += (run[e]+pad-1)&~(pad-1); }
        aoff[NEXP]=off;
    }
}

/* ---------------- scatter token->row maps ---------------- */
__global__ void k_build(const int* __restrict__ eidx, const int* __restrict__ slot,
                        const int* __restrict__ aoff,
                        int* __restrict__ tor, int* __restrict__ row_of){
    int t = blockIdx.x*blockDim.x + threadIdx.x;      /* < 2N */
    int e = eidx[t];
    int row = aoff[e] + slot[t];
    tor[row] = t>>1;
    row_of[t] = row;
}

/* ============ 256-wide bf16 GEMM, 8 waves, double-buffered LDS ============
   Tile = (MREP*32) rows x 256 cols, BK=64, 2-phase: stage(t+1) -> MFMA(t) ->
   one barrier. Out = [silu](A * B^T).                                        */
template<int MREP, bool GATHER, bool SILU>
__global__ __launch_bounds__(512)
void k_gemm256(const unsigned short* __restrict__ Abase,
               const int* __restrict__ tor,
               const unsigned short* __restrict__ zeropg,
               const unsigned short* __restrict__ Bbase,
               const int* __restrict__ aoff,
               unsigned short* __restrict__ Out,
               int Kdim, int ldo, int bn_rows)
{
    constexpr int BMR = MREP*32;
    int row0  = blockIdx.x * BMR;
    int total = aoff[NEXP];
    if(row0 >= total) return;
    int e = 0;
    while(e < NEXP-1 && row0 >= aoff[e+1]) e++;
    int col0 = blockIdx.y * 256;

    __shared__ unsigned short sA[2][BMR*64];   /* [row][64 bf16], linear 128B rows */
    __shared__ unsigned short sB[2][256*64];

    int tid = threadIdx.x;
    int l = tid & 63, w = tid >> 6;       /* 8 waves */
    int wm = w >> 2, wn = w & 3;          /* 2 x 4 wave grid */
    int lr = l & 15, lk = (l>>4)*8;
    int sub = l >> 3, c16 = l & 7;        /* staging: 8 rows x 8 x 16B per call */

    /* per-wave staging pointers: segment s = 8 rows; wave w takes segs w+8*i */
    const char* aptr[MREP/2];
    #pragma unroll
    for(int i=0;i<MREP/2;i++){
        int row = (w + 8*i)*8 + sub;
        if(GATHER){
            int tok = tor[row0 + row];
            aptr[i] = (tok>=0) ? (const char*)(Abase + (size_t)tok*Kdim)
                               : (const char*)zeropg;
        } else {
            aptr[i] = (const char*)(Abase + (size_t)(row0+row)*Kdim);
        }
        aptr[i] += c16*16;
    }
    const char* bptr[4];
    #pragma unroll
    for(int i=0;i<4;i++){
        int row = (w + 8*i)*8 + sub;
        bptr[i] = (const char*)(Bbase + ((size_t)e*bn_rows + col0 + row)*Kdim) + c16*16;
    }

    f32x4 acc[MREP][4];
    #pragma unroll
    for(int m=0;m<MREP;m++)
        #pragma unroll
        for(int n=0;n<4;n++) acc[m][n] = (f32x4){0.f,0.f,0.f,0.f};

    int nt = Kdim/64;
    /* prologue: stage K-tile 0 into buf 0 */
    #pragma unroll
    for(int i=0;i<MREP/2;i++)
        gl_lds16(aptr[i], (void*)(&sA[0][0] + (w+8*i)*512));
    #pragma unroll
    for(int i=0;i<4;i++)
        gl_lds16(bptr[i], (void*)(&sB[0][0] + (w+8*i)*512));
    __syncthreads();

    for(int t=0; t<nt; ++t){
        int cur = t & 1;
        if(t+1 < nt){
            int nxt = cur^1;
            size_t koff = (size_t)(t+1)*128;   /* 64 bf16 = 128 B */
            #pragma unroll
            for(int i=0;i<MREP/2;i++)
                gl_lds16(aptr[i]+koff, (void*)(&sA[nxt][0] + (w+8*i)*512));
            #pragma unroll
            for(int i=0;i<4;i++)
                gl_lds16(bptr[i]+koff, (void*)(&sB[nxt][0] + (w+8*i)*512));
        }
        #pragma unroll
        for(int kk=0; kk<2; kk++){
            short8 af[MREP], bfr[4];
            #pragma unroll
            for(int m=0;m<MREP;m++)
                af[m] = *reinterpret_cast<const short8*>(
                    &sA[cur][0] + (wm*(MREP*16) + m*16 + lr)*64 + kk*32 + lk);
            #pragma unroll
            for(int n=0;n<4;n++)
                bfr[n] = *reinterpret_cast<const short8*>(
                    &sB[cur][0] + (wn*64 + n*16 + lr)*64 + kk*32 + lk);
            #pragma unroll
            for(int m=0;m<MREP;m++)
                #pragma unroll
                for(int n=0;n<4;n++)
                    acc[m][n] = __builtin_amdgcn_mfma_f32_16x16x32_bf16(af[m], bfr[n], acc[m][n], 0,0,0);
        }
        __syncthreads();
    }

    /* epilogue: C/D layout col=lane&15, row=(lane>>4)*4+j */
    int orow0 = row0 + wm*(MREP*16) + (l>>4)*4;
    int ocol0 = col0 + wn*64 + lr;
    #pragma unroll
    for(int m=0;m<MREP;m++){
        #pragma unroll
        for(int n=0;n<4;n++){
            f32x4 v = acc[m][n];
            #pragma unroll
            for(int j=0;j<4;j++){
                float val = v[j];
                if(SILU) val = val / (1.f + expf(-val));
                size_t idx = (size_t)(orow0 + m*16 + j)*(size_t)ldo + (size_t)(ocol0 + n*16);
                Out[idx] = f2b(val);
            }
        }
    }
}

/* ---------------- fallback 128x128 GEMM (round-5 proven) ---------------- */
template<bool GATHER, bool SILU>
__global__ __launch_bounds__(256)
void k_gemm_fast(const unsigned short* __restrict__ Abase,
                 const int* __restrict__ tor,
                 const unsigned short* __restrict__ zeropg,
                 const unsigned short* __restrict__ Bbase,
                 const int* __restrict__ aoff,
                 unsigned short* __restrict__ Out,
                 int Kdim, int ldo, int bn_rows)
{
    int row0  = blockIdx.x * 128;
    int total = aoff[NEXP];
    if(row0 >= total) return;
    int e = 0;
    while(e < NEXP-1 && row0 >= aoff[e+1]) e++;
    int col0 = blockIdx.y * 128;

    __shared__ unsigned short sA[128*64];
    __shared__ unsigned short sB[128*64];

    int tid = threadIdx.x;
    int l = tid & 63, w = tid >> 6;
    int wr = w >> 1, wc = w & 1;
    int lr = l & 15, lk = (l>>4)*8;
    int sub = l >> 3, c16 = l & 7;
    const char* abase[4];
    const char* bbase[4];
    #pragma unroll
    for(int i=0;i<4;i++){
        int row = w*32 + i*8 + sub;
        if(GATHER){
            int tok = tor[row0 + row];
            abase[i] = (tok>=0) ? (const char*)(Abase + (size_t)tok*Kdim)
                                : (const char*)zeropg;
        } else {
            abase[i] = (const char*)(Abase + (size_t)(row0+row)*Kdim);
        }
        abase[i] += c16*16;
        bbase[i] = (const char*)(Bbase + ((size_t)e*bn_rows + col0 + row)*Kdim) + c16*16;
    }

    f32x4 acc[4][4];
    #pragma unroll
    for(int m=0;m<4;m++)
        #pragma unroll
        for(int n=0;n<4;n++) acc[m][n] = (f32x4){0.f,0.f,0.f,0.f};

    for(int k0=0; k0<Kdim; k0+=64){
        size_t koff = (size_t)k0*2;
        #pragma unroll
        for(int i=0;i<4;i++){
            gl_lds16(abase[i]+koff, (void*)(sA + (w*4+i)*512));
            gl_lds16(bbase[i]+koff, (void*)(sB + (w*4+i)*512));
        }
        __syncthreads();
        #pragma unroll
        for(int kk=0; kk<2; kk++){
            short8 af[4], bfr[4];
            #pragma unroll
            for(int m=0;m<4;m++)
                af[m] = *reinterpret_cast<const short8*>(sA + (wr*64 + m*16 + lr)*64 + kk*32 + lk);
            #pragma unroll
            for(int n=0;n<4;n++)
                bfr[n] = *reinterpret_cast<const short8*>(sB + (wc*64 + n*16 + lr)*64 + kk*32 + lk);
            #pragma unroll
            for(int m=0;m<4;m++)
                #pragma unroll
                for(int n=0;n<4;n++)
                    acc[m][n] = __builtin_amdgcn_mfma_f32_16x16x32_bf16(af[m], bfr[n], acc[m][n], 0,0,0);
        }
        __syncthreads();
    }

    int orow_base = row0 + wr*64 + (l>>4)*4;
    int ocol_base = col0 + wc*64 + lr;
    #pragma unroll
    for(int m=0;m<4;m++){
        #pragma unroll
        for(int n=0;n<4;n++){
            f32x4 v = acc[m][n];
            #pragma unroll
            for(int j=0;j<4;j++){
                float val = v[j];
                if(SILU) val = val / (1.f + expf(-val));
                size_t idx = (size_t)(orow_base + m*16 + j)*(size_t)ldo + (size_t)(ocol_base + n*16);
                Out[idx] = f2b(val);
            }
        }
    }
}

/* ---------------- combine: y[n] = p0*hout[r0] + p1*hout[r1] ---------------- */
__global__ void k_combine(const unsigned short* __restrict__ hout,
                          const int* __restrict__ row_of,
                          const float* __restrict__ probs,
                          float* __restrict__ y){
    int i = blockIdx.x*blockDim.x + threadIdx.x;   /* N*C/8 */
    int n  = i >> 7;
    int c8 = (i & 127) * 8;
    int r0 = row_of[2*n], r1 = row_of[2*n+1];
    float p0 = probs[2*n], p1 = probs[2*n+1];
    uint4 h0 = *reinterpret_cast<const uint4*>(hout + (size_t)r0*CDIM + c8);
    uint4 h1 = *reinterpret_cast<const uint4*>(hout + (size_t)r1*CDIM + c8);
    const unsigned short* a = reinterpret_cast<const unsigned short*>(&h0);
    const unsigned short* b = reinterpret_cast<const unsigned short*>(&h1);
    float4 o0, o1;
    o0.x = p0*b2f(a[0]) + p1*b2f(b[0]);
    o0.y = p0*b2f(a[1]) + p1*b2f(b[1]);
    o0.z = p0*b2f(a[2]) + p1*b2f(b[2]);
    o0.w = p0*b2f(a[3]) + p1*b2f(b[3]);
    o1.x = p0*b2f(a[4]) + p1*b2f(b[4]);
    o1.y = p0*b2f(a[5]) + p1*b2f(b[5]);
    o1.z = p0*b2f(a[6]) + p1*b2f(b[6]);
    o1.w = p0*b2f(a[7]) + p1*b2f(b[7]);
    float4* dst = reinterpret_cast<float4*>(y + (size_t)n*CDIM + c8);
    dst[0] = o0; dst[1] = o1;
}

extern "C" void kernel_launch(void* const* d_in, const int* in_sizes, int n_in,
                              void* d_out, int out_size, void* d_ws, size_t ws_size,
                              hipStream_t stream){
    const float* x  = (const float*)d_in[0];
    const float* gw = (const float*)d_in[1];
    const float* w1 = (const float*)d_in[2];
    const float* w2 = (const float*)d_in[3];
    float* y = (float*)d_out;
    char* ws = (char*)d_ws;

    /* control block (first 1 MB) */
    int*   aoff   = (int*)(ws + 64);
    int*   eidx   = (int*)(ws + 256);
    float* probs  = (float*)(ws + 256 + 1*65536);
    int*   slot   = (int*)(ws + 256 + 2*65536);
    int*   row_of = (int*)(ws + 256 + 3*65536);
    int*   tor    = (int*)(ws + 256 + 4*65536);
    unsigned short* zeropg = (unsigned short*)(ws + 512*1024);   /* 4 KB zeros */

    const size_t SZ_XB   = (size_t)NTOK*CDIM*2;          /* 16.78 MB */
    const size_t SZ_W    = (size_t)NEXP*FFD*CDIM*2;      /* 33.55 MB each */
    const size_t SZ_H256 = (size_t)RMAX*FFD*2;           /* 75.50 MB */
    const size_t SZ_H128 = (size_t)RMAX128*FFD*2;        /* 71.30 MB */
    const size_t CTRL    = 1<<20;

    unsigned short* Xb   = (unsigned short*)(ws + CTRL);
    unsigned short* W1b  = (unsigned short*)(ws + CTRL + SZ_XB);
    unsigned short* W2b  = (unsigned short*)(ws + CTRL + SZ_XB + SZ_W);
    unsigned short* H    = (unsigned short*)(ws + CTRL + SZ_XB + 2*SZ_W);
    unsigned short* hout = Xb;   /* aliases Xb+W1b, both dead before GEMM2 */

    hipMemsetAsync(tor, 0xFF, RMAX*sizeof(int), stream);
    hipMemsetAsync(zeropg, 0, 4096, stream);

    int n8 = NEXP*FFD*CDIM/8;
    k_cvt<<<n8/256, 256, 0, stream>>>(w1, W1b, n8);
    k_cvt<<<n8/256, 256, 0, stream>>>(w2, W2b, n8);
    k_gate<<<NTOK/4, 256, 0, stream>>>(x, gw, Xb, eidx, probs);

    if(ws_size >= CTRL + SZ_XB + 2*SZ_W + SZ_H256){
        /* 256-wide path */
        k_rank<<<1, 1024, 0, stream>>>(eidx, slot, aoff, 256);
        k_build<<<NTOK*2/256, 256, 0, stream>>>(eidx, slot, aoff, tor, row_of);

        dim3 g1(RMAX/256, FFD/256);
        k_gemm256<8, true,  true ><<<g1, 512, 0, stream>>>(Xb, tor, zeropg, W1b, aoff, H,    CDIM, FFD,  FFD);
        dim3 g2(RMAX/128, CDIM/256);
        k_gemm256<4, false, false><<<g2, 512, 0, stream>>>(H,  tor, zeropg, W2b, aoff, hout, FFD,  CDIM, CDIM);
    } else {
        /* fallback: proven round-5 128x128 path */
        k_rank<<<1, 1024, 0, stream>>>(eidx, slot, aoff, 128);
        k_build<<<NTOK*2/256, 256, 0, stream>>>(eidx, slot, aoff, tor, row_of);

        dim3 g1(RMAX128/128, FFD/128);
        k_gemm_fast<true,  true ><<<g1, 256, 0, stream>>>(Xb, tor, zeropg, W1b, aoff, H,    CDIM, FFD,  FFD);
        dim3 g2(RMAX128/128, CDIM/128);
        k_gemm_fast<false, false><<<g2, 256, 0, stream>>>(H,  tor, zeropg, W2b, aoff, hout, FFD,  CDIM, CDIM);
    }

    k_combine<<<NTOK*CDIM/8/256, 256, 0, stream>>>(hout, row_of, probs, y);
}

// Round 7
// 270.734 us; speedup vs baseline: 1.4827x; 1.4827x over previous
//
#include <hip/hip_runtime.h>
#include <hip/hip_bf16.h>
#include <math.h>

#define NTOK 8192
#define CDIM 1024
#define NEXP 8
#define FFD  2048
#define BM   128
#define RMAX (NTOK*2 + NEXP*BM)   /* 17408 padded rows max */

typedef __attribute__((ext_vector_type(8))) short short8;
typedef __attribute__((ext_vector_type(4))) float f32x4;

__device__ __forceinline__ unsigned short f2b(float f){
    __hip_bfloat16 b = __float2bfloat16(f);
    return *reinterpret_cast<unsigned short*>(&b);
}
__device__ __forceinline__ float b2f(unsigned short u){
    __hip_bfloat16 b = *reinterpret_cast<__hip_bfloat16*>(&u);
    return __bfloat162float(b);
}

/* async global->LDS, 16B per lane; LDS dest = wave-uniform base + lane*16 */
__device__ __forceinline__ void gl_lds16(const void* g, void* l){
    __builtin_amdgcn_global_load_lds(
        (const __attribute__((address_space(1))) unsigned int*)g,
        (__attribute__((address_space(3))) unsigned int*)l, 16, 0, 0);
}

/* ---------------- f32 -> bf16 bulk convert (weights) ---------------- */
__global__ void k_cvt(const float* __restrict__ src, unsigned short* __restrict__ dst, int n8){
    int i = blockIdx.x*blockDim.x + threadIdx.x;
    if(i >= n8) return;
    const float4* s = reinterpret_cast<const float4*>(src) + (size_t)i*2;
    float4 a = s[0], b = s[1];
    ushort4 o0 = { f2b(a.x), f2b(a.y), f2b(a.z), f2b(a.w) };
    ushort4 o1 = { f2b(b.x), f2b(b.y), f2b(b.z), f2b(b.w) };
    ushort4* d = reinterpret_cast<ushort4*>(dst) + (size_t)i*2;
    d[0] = o0; d[1] = o1;
}

/* ---------------- fused gate + x->bf16 (NO atomics) ---------------- */
__global__ void k_gate(const float* __restrict__ x, const float* __restrict__ gw,
                       unsigned short* __restrict__ Xb,
                       int* __restrict__ eidx, float* __restrict__ probs){
    int tok  = blockIdx.x*4 + (threadIdx.x>>6);
    int l    = threadIdx.x & 63;
    const float4* xr  = reinterpret_cast<const float4*>(x + (size_t)tok*CDIM);
    ushort4*      xbw = reinterpret_cast<ushort4*>(Xb + (size_t)tok*CDIM);
    float acc[NEXP];
    #pragma unroll
    for(int e=0;e<NEXP;e++) acc[e]=0.f;
    #pragma unroll
    for(int i=0;i<4;i++){
        float4 v = xr[l + 64*i];
        ushort4 o = { f2b(v.x), f2b(v.y), f2b(v.z), f2b(v.w) };
        xbw[l + 64*i] = o;
        #pragma unroll
        for(int e=0;e<NEXP;e++){
            float4 g = reinterpret_cast<const float4*>(gw + e*CDIM)[l + 64*i];
            acc[e] += v.x*g.x + v.y*g.y + v.z*g.z + v.w*g.w;
        }
    }
    #pragma unroll
    for(int e=0;e<NEXP;e++){
        #pragma unroll
        for(int off=32; off; off>>=1) acc[e] += __shfl_xor(acc[e], off);
    }
    if(l==0){
        int e0=0; float s0=acc[0];
        #pragma unroll
        for(int e=1;e<NEXP;e++) if(acc[e]>s0){s0=acc[e]; e0=e;}
        int e1=-1; float s1=-1e30f;
        #pragma unroll
        for(int e=0;e<NEXP;e++) if(e!=e0 && acc[e]>s1){s1=acc[e]; e1=e;}
        float p0 = 1.f/(1.f + expf(s1-s0));
        float p1 = 1.f - p0;
        eidx[2*tok]=e0;  eidx[2*tok+1]=e1;
        probs[2*tok]=p0; probs[2*tok+1]=p1;
    }
}

/* ---------------- deterministic rank (slot) + aoff: ONE block, no atomics ---- */
__global__ void k_rank(const int* __restrict__ eidx, int* __restrict__ slot,
                       int* __restrict__ aoff, int pad){
    __shared__ int run[NEXP];
    __shared__ int wavehist[16][NEXP];
    int tid  = threadIdx.x;              /* 1024 threads = 16 waves */
    int lane = tid & 63, w = tid >> 6;
    if(tid < NEXP) run[tid] = 0;
    __syncthreads();
    for(int iter=0; iter<(2*NTOK)/1024; iter++){
        int t = iter*1024 + tid;
        int e = eidx[t];
        unsigned long long mymask = 0;
        #pragma unroll
        for(int ee=0; ee<NEXP; ee++){
            unsigned long long m = __ballot(e==ee);
            if(ee==e) mymask = m;
            if(lane==0) wavehist[w][ee] = __popcll(m);
        }
        int lanerank = __popcll(mymask & ((1ULL<<lane)-1ULL));
        __syncthreads();
        if(tid < NEXP){
            int base = run[tid];
            #pragma unroll
            for(int ww=0; ww<16; ww++){
                int c = wavehist[ww][tid];
                wavehist[ww][tid] = base;
                base += c;
            }
            run[tid] = base;
        }
        __syncthreads();
        slot[t] = wavehist[w][e] + lanerank;
    }
    __syncthreads();
    if(tid==0){
        int off=0;
        for(int e=0;e<NEXP;e++){ aoff[e]=off; off += (run[e]+pad-1)&~(pad-1); }
        aoff[NEXP]=off;
    }
}

/* ---------------- scatter token->row maps ---------------- */
__global__ void k_build(const int* __restrict__ eidx, const int* __restrict__ slot,
                        const int* __restrict__ aoff,
                        int* __restrict__ tor, int* __restrict__ row_of){
    int t = blockIdx.x*blockDim.x + threadIdx.x;      /* < 2N */
    int e = eidx[t];
    int row = aoff[e] + slot[t];
    tor[row] = t>>1;
    row_of[t] = row;
}

/* ---------- 128x128 bf16 GEMM: gl_lds staging + chunk-XOR LDS swizzle --------
   Swizzle (rule #21, both-sides-or-neither): LDS dest stays LINEAR (required by
   global_load_lds); the global SOURCE chunk within each 128B row is permuted by
   c ^ (row&7); the ds_read applies the same XOR. Kills the 16-way stride-128B
   bank conflict (G4: byte ^= (row&7)<<4, verified +89% on attn K-tile).       */
template<bool GATHER, bool SILU>
__global__ __launch_bounds__(256)
void k_gemm_fast(const unsigned short* __restrict__ Abase,
                 const int* __restrict__ tor,
                 const unsigned short* __restrict__ zeropg,
                 const unsigned short* __restrict__ Bbase,
                 const int* __restrict__ aoff,
                 unsigned short* __restrict__ Out,
                 int Kdim, int ldo, int bn_rows)
{
    int row0  = blockIdx.x * BM;
    int total = aoff[NEXP];
    if(row0 >= total) return;
    int e = 0;
    while(e < NEXP-1 && row0 >= aoff[e+1]) e++;
    int col0 = blockIdx.y * 128;

    __shared__ unsigned short sA[128*64];   /* [row][64 bf16], 128B rows, linear */
    __shared__ unsigned short sB[128*64];

    int tid = threadIdx.x;
    int l = tid & 63, w = tid >> 6;
    int wr = w >> 1, wc = w & 1;
    int lr = l & 15;

    /* staging geometry: wave w fills segments w*4+i (i=0..3), 1KB each =
       rows w*32+i*8 .. +7. lane l -> row sub l>>3, 16B chunk l&7.
       SOURCE pre-swizzle: lane (sub,c16) loads global chunk (c16 ^ sub). */
    int sub = l >> 3, c16 = l & 7;
    int csw = (c16 ^ sub) * 16;             /* swizzled source byte offset */
    const char* abase[4];
    const char* bbase[4];
    #pragma unroll
    for(int i=0;i<4;i++){
        int row = w*32 + i*8 + sub;
        if(GATHER){
            int tok = tor[row0 + row];
            abase[i] = (tok>=0) ? (const char*)(Abase + (size_t)tok*Kdim)
                                : (const char*)zeropg;
        } else {
            abase[i] = (const char*)(Abase + (size_t)(row0+row)*Kdim);
        }
        abase[i] += csw;
        bbase[i] = (const char*)(Bbase + ((size_t)e*bn_rows + col0 + row)*Kdim) + csw;
    }

    /* read-side swizzle pieces: chunk index C = kk*4 + (l>>4); read at
       LDS chunk C ^ (row&7); row&7 == lr&7 for all fragment rows. */
    int kgrp = l >> 4;          /* 0..3 */
    int lsw  = lr & 7;

    f32x4 acc[4][4];
    #pragma unroll
    for(int m=0;m<4;m++)
        #pragma unroll
        for(int n=0;n<4;n++) acc[m][n] = (f32x4){0.f,0.f,0.f,0.f};

    for(int k0=0; k0<Kdim; k0+=64){
        size_t koff = (size_t)k0*2;
        #pragma unroll
        for(int i=0;i<4;i++){
            gl_lds16(abase[i]+koff, (void*)(sA + (w*4+i)*512));
            gl_lds16(bbase[i]+koff, (void*)(sB + (w*4+i)*512));
        }
        __syncthreads();
        __builtin_amdgcn_s_setprio(1);
        #pragma unroll
        for(int kk=0; kk<2; kk++){
            int swc = ((kk<<2) | kgrp) ^ lsw;   /* swizzled 16B-chunk index */
            short8 af[4], bfr[4];
            #pragma unroll
            for(int m=0;m<4;m++)
                af[m] = *reinterpret_cast<const short8*>(sA + (wr*64 + m*16 + lr)*64 + swc*8);
            #pragma unroll
            for(int n=0;n<4;n++)
                bfr[n] = *reinterpret_cast<const short8*>(sB + (wc*64 + n*16 + lr)*64 + swc*8);
            #pragma unroll
            for(int m=0;m<4;m++)
                #pragma unroll
                for(int n=0;n<4;n++)
                    acc[m][n] = __builtin_amdgcn_mfma_f32_16x16x32_bf16(af[m], bfr[n], acc[m][n], 0,0,0);
        }
        __builtin_amdgcn_s_setprio(0);
        __syncthreads();
    }

    /* epilogue: C/D layout col=lane&15, row=(lane>>4)*4+j  (m89-verified) */
    int orow_base = row0 + wr*64 + (l>>4)*4;
    int ocol_base = col0 + wc*64 + lr;
    #pragma unroll
    for(int m=0;m<4;m++){
        #pragma unroll
        for(int n=0;n<4;n++){
            f32x4 v = acc[m][n];
            #pragma unroll
            for(int j=0;j<4;j++){
                float val = v[j];
                if(SILU) val = val / (1.f + expf(-val));
                size_t idx = (size_t)(orow_base + m*16 + j)*(size_t)ldo + (size_t)(ocol_base + n*16);
                Out[idx] = f2b(val);
            }
        }
    }
}

/* ---------------- combine: y[n] = p0*hout[r0] + p1*hout[r1] ---------------- */
__global__ void k_combine(const unsigned short* __restrict__ hout,
                          const int* __restrict__ row_of,
                          const float* __restrict__ probs,
                          float* __restrict__ y){
    int i = blockIdx.x*blockDim.x + threadIdx.x;   /* N*C/8 */
    int n  = i >> 7;
    int c8 = (i & 127) * 8;
    int r0 = row_of[2*n], r1 = row_of[2*n+1];
    float p0 = probs[2*n], p1 = probs[2*n+1];
    uint4 h0 = *reinterpret_cast<const uint4*>(hout + (size_t)r0*CDIM + c8);
    uint4 h1 = *reinterpret_cast<const uint4*>(hout + (size_t)r1*CDIM + c8);
    const unsigned short* a = reinterpret_cast<const unsigned short*>(&h0);
    const unsigned short* b = reinterpret_cast<const unsigned short*>(&h1);
    float4 o0, o1;
    o0.x = p0*b2f(a[0]) + p1*b2f(b[0]);
    o0.y = p0*b2f(a[1]) + p1*b2f(b[1]);
    o0.z = p0*b2f(a[2]) + p1*b2f(b[2]);
    o0.w = p0*b2f(a[3]) + p1*b2f(b[3]);
    o1.x = p0*b2f(a[4]) + p1*b2f(b[4]);
    o1.y = p0*b2f(a[5]) + p1*b2f(b[5]);
    o1.z = p0*b2f(a[6]) + p1*b2f(b[6]);
    o1.w = p0*b2f(a[7]) + p1*b2f(b[7]);
    float4* dst = reinterpret_cast<float4*>(y + (size_t)n*CDIM + c8);
    dst[0] = o0; dst[1] = o1;
}

extern "C" void kernel_launch(void* const* d_in, const int* in_sizes, int n_in,
                              void* d_out, int out_size, void* d_ws, size_t ws_size,
                              hipStream_t stream){
    const float* x  = (const float*)d_in[0];
    const float* gw = (const float*)d_in[1];
    const float* w1 = (const float*)d_in[2];
    const float* w2 = (const float*)d_in[3];
    float* y = (float*)d_out;
    char* ws = (char*)d_ws;

    /* control block (first 1 MB) */
    int*   aoff   = (int*)(ws + 64);
    int*   eidx   = (int*)(ws + 256);
    float* probs  = (float*)(ws + 256 + 1*65536);
    int*   slot   = (int*)(ws + 256 + 2*65536);
    int*   row_of = (int*)(ws + 256 + 3*65536);
    int*   tor    = (int*)(ws + 256 + 4*65536);
    unsigned short* zeropg = (unsigned short*)(ws + 512*1024);   /* 4 KB zeros */

    const size_t SZ_XB  = (size_t)NTOK*CDIM*2;          /* 16.78 MB */
    const size_t SZ_W   = (size_t)NEXP*FFD*CDIM*2;      /* 33.55 MB each */
    const size_t CTRL   = 1<<20;

    unsigned short* Xb   = (unsigned short*)(ws + CTRL);
    unsigned short* W1b  = (unsigned short*)(ws + CTRL + SZ_XB);
    unsigned short* W2b  = (unsigned short*)(ws + CTRL + SZ_XB + SZ_W);
    unsigned short* H    = (unsigned short*)(ws + CTRL + SZ_XB + 2*SZ_W);
    unsigned short* hout = Xb;   /* aliases Xb+W1b, both dead before GEMM2 */

    hipMemsetAsync(tor, 0xFF, RMAX*sizeof(int), stream);
    hipMemsetAsync(zeropg, 0, 4096, stream);

    int n8 = NEXP*FFD*CDIM/8;
    k_cvt<<<n8/256, 256, 0, stream>>>(w1, W1b, n8);
    k_cvt<<<n8/256, 256, 0, stream>>>(w2, W2b, n8);
    k_gate<<<NTOK/4, 256, 0, stream>>>(x, gw, Xb, eidx, probs);
    k_rank<<<1, 1024, 0, stream>>>(eidx, slot, aoff, BM);
    k_build<<<NTOK*2/256, 256, 0, stream>>>(eidx, slot, aoff, tor, row_of);

    dim3 g1(RMAX/BM, FFD/128);
    k_gemm_fast<true,  true ><<<g1, 256, 0, stream>>>(Xb, tor, zeropg, W1b, aoff, H,    CDIM, FFD,  FFD);
    dim3 g2(RMAX/BM, CDIM/128);
    k_gemm_fast<false, false><<<g2, 256, 0, stream>>>(H,  tor, zeropg, W2b, aoff, hout, FFD,  CDIM, CDIM);

    k_combine<<<NTOK*CDIM/8/256, 256, 0, stream>>>(hout, row_of, probs, y);
}